// Round 12
// baseline (329932.935 us; speedup 1.0000x reference)
//
#include <hip/hip_runtime.h>
#include <stdint.h>

typedef unsigned long long u64;
typedef float f32x32 __attribute__((ext_vector_type(32)));
typedef float f32x16 __attribute__((ext_vector_type(16)));

#define T_TOTAL 65536
#define ISZ 256
#define HSZ 512
#define NWORK 16
#define SLICE 32    // HSZ / NWORK
#define NTHR 512    // 8 waves -> 256-reg budget (R10 lesson)
#define SPIN 511    // counter spinner (wave 7)
#define XB 8        // x batch depth / out batch depth

// LDS skew (word index): +4 words per row -> max 2-way bank aliasing (free).
__device__ __forceinline__ int HSW(int i) { return i + ((i >> 5) << 2); }
__device__ __forceinline__ int XSW(int i) { return i + ((i >> 4) << 2); }

struct Ctl { int grank; int chosen; int fastctr; int done; int slowctr; int pad[11]; };

// TCC-executed one-shot RMW read (add 0, sc0 returns old). Inline asm so
// InstCombine cannot demote to an (L1-stale) atomic load — R3/4/5/7 evidence.
__device__ __forceinline__ u64 rmw_read(const u64* p) {
  u64 q, zero = 0;
  asm volatile("global_atomic_add_x2 %0, %1, %2, off sc0\n\t"
               "s_waitcnt vmcnt(0)"
               : "=&v"(q) : "v"(p), "v"(zero) : "memory");
  return q;
}
__device__ __forceinline__ void spin_cnt(const u64* p, u64 target, long long& budget) {
  for (;;) {
    u64 q = rmw_read(p);
    if (q >= target) break;
    if (--budget <= 0) break;
  }
}
__device__ __forceinline__ void cnt_bump(u64* p) {
  u64 one = 1;
  asm volatile("global_atomic_add_x2 %0, %1, off" :: "v"(p), "v"(one) : "memory");
}

#define IGDOTS(B_, K_)                                                         \
  do {                                                                         \
    _Pragma("unroll")                                                          \
    for (int u = 0; u < 4; ++u) {                                              \
      float4 xv = *(const float4*)&x_lds[B_][K_][XSW(seg * 16 + u * 4)];       \
      a0 += wi0[u*4+0]*xv.x + wi0[u*4+1]*xv.y + wi0[u*4+2]*xv.z + wi0[u*4+3]*xv.w; \
      a1 += wi1[u*4+0]*xv.x + wi1[u*4+1]*xv.y + wi1[u*4+2]*xv.z + wi1[u*4+3]*xv.w; \
      a2 += wi2[u*4+0]*xv.x + wi2[u*4+1]*xv.y + wi2[u*4+2]*xv.z + wi2[u*4+3]*xv.w; \
    }                                                                          \
  } while (0)

#define MATVEC_BFLY()                                                          \
  do {                                                                         \
    _Pragma("unroll")                                                          \
    for (int u = 0; u < 8; ++u) {                                              \
      float4 hv = *(const float4*)&h_lds[HSW(seg * 32 + u * 4)];               \
      a0 += wh0[u*4+0]*hv.x + wh0[u*4+1]*hv.y + wh0[u*4+2]*hv.z + wh0[u*4+3]*hv.w; \
      a1 += wh1[u*4+0]*hv.x + wh1[u*4+1]*hv.y + wh1[u*4+2]*hv.z + wh1[u*4+3]*hv.w; \
      a3 += wh2[u*4+0]*hv.x + wh2[u*4+1]*hv.y + wh2[u*4+2]*hv.z + wh2[u*4+3]*hv.w; \
    }                                                                          \
    _Pragma("unroll")                                                          \
    for (int p = 0; p < 4; ++p) {                                              \
      int m = 1 << p;                                                          \
      a0 += __shfl_xor(a0, m, 64);                                             \
      a1 += __shfl_xor(a1, m, 64);                                             \
      a2 += __shfl_xor(a2, m, 64);                                             \
      a3 += __shfl_xor(a3, m, 64);                                             \
    }                                                                          \
  } while (0)

// ---------------------------------------------------------------------------
// Persistent fused GRU scan, 16 blocks x 512 threads, counter+one-shot-fetch
// protocol (R12): publishers pack 2 f32 per 8B slot (16 swaps/block) and bump
// a global counter (+1 per publisher after its swap retires; target 256*s);
// ONE spinner thread per block watches the counter; after it passes, 256
// threads/block fetch the 256 slots with exactly one RMW each (no respins).
// Serviced atomics/step: ~4.6K vs R11's 21.6K (TCC atomic pipe saturated).
// out[] stores batched 8 steps via hq LDS; x loaded 8 rows/batch by wave 7.
//
// Safety (2 barriers/step): fetch(s) happens after counter>=256s, i.e. after
// every block's publishes of h_s retired at the TCC. A block writes slot
// parity p for h_{s+1} only after its spin saw counter>=256s, which implies
// all blocks' fetches of h_{s-1} (same parity p) completed (program order:
// fetch(s-1) < publish(s-1->s) < spin(s) pass). h_lds/x_lds/hq reuse is
// ordered by B1/B2 as annotated. Spin fuse: fail visibly, never wedge.
// ---------------------------------------------------------------------------
__global__ __launch_bounds__(NTHR, 1) void gru_fused(
    const float* __restrict__ xs, const float* __restrict__ w_ih,
    const float* __restrict__ w_hh, const float* __restrict__ bias,
    const float* __restrict__ bias_n, u64* __restrict__ hfast,
    u64* __restrict__ hcnt, u64* __restrict__ hslow,
    Ctl* __restrict__ ctl, float* __restrict__ out) {
  const int tid = threadIdx.x;
  const int seg = tid & 15;   // K-segment: h[32*seg..+32), x[16*seg..+16)
  const int rg  = tid >> 4;   // unit within slice (0..31)

  __shared__ int s_role, s_fast;
  __shared__ __align__(16) float x_lds[2][XB][320];
  __shared__ __align__(16) float h_lds[576];
  __shared__ float hq[32 * 9];   // [unit][step&7], padded 9 to spread banks

  // ---- election: verify 16 blocks on one XCD, else agent-scope fallback
  if (tid == 0) {
    unsigned xcc = 0;
    asm volatile("s_getreg_b32 %0, hwreg(HW_REG_XCC_ID)" : "=s"(xcc));
    long long eb = 100000000;
    int rank = __hip_atomic_fetch_add(&ctl->grank, 1, __ATOMIC_RELAXED,
                                      __HIP_MEMORY_SCOPE_AGENT);
    if (rank == 0)
      __hip_atomic_store(&ctl->chosen, (int)xcc + 1, __ATOMIC_RELEASE,
                         __HIP_MEMORY_SCOPE_AGENT);
    int chosen;
    do { chosen = __hip_atomic_load(&ctl->chosen, __ATOMIC_ACQUIRE,
                                    __HIP_MEMORY_SCOPE_AGENT); }
    while (chosen == 0 && --eb > 0);
    int fr = -1;
    if ((int)xcc == chosen - 1)
      fr = __hip_atomic_fetch_add(&ctl->fastctr, 1, __ATOMIC_RELAXED,
                                  __HIP_MEMORY_SCOPE_AGENT);
    __hip_atomic_fetch_add(&ctl->done, 1, __ATOMIC_ACQ_REL,
                           __HIP_MEMORY_SCOPE_AGENT);
    int dn;
    do { dn = __hip_atomic_load(&ctl->done, __ATOMIC_ACQUIRE,
                                __HIP_MEMORY_SCOPE_AGENT); }
    while (dn < (int)gridDim.x && --eb > 0);
    int fc = __hip_atomic_load(&ctl->fastctr, __ATOMIC_ACQUIRE,
                               __HIP_MEMORY_SCOPE_AGENT);
    int fast = (fc >= NWORK && dn >= (int)gridDim.x) ? 1 : 0;
    int role = -1;
    if (fast) {
      if (fr >= 0 && fr < NWORK) role = fr;
    } else {
      int sr = __hip_atomic_fetch_add(&ctl->slowctr, 1, __ATOMIC_RELAXED,
                                      __HIP_MEMORY_SCOPE_AGENT);
      if (sr < NWORK) role = sr;
    }
    s_role = role; s_fast = fast;
  }
  __syncthreads();
  const int role = s_role;   // uniform per block
  const int fast = s_fast;
  if (role < 0) return;      // whole block exits together

  // ---- weights into registers (ext_vector, static indexing; R8-proven) ----
  const int myunit = role * SLICE + rg;
  f32x32 wh0, wh1, wh2;
  f32x16 wi0, wi1, wi2;
  {
    const float* h0 = w_hh + (size_t)(0 * HSZ + myunit) * HSZ + seg * 32;
    const float* h1 = w_hh + (size_t)(1 * HSZ + myunit) * HSZ + seg * 32;
    const float* h2 = w_hh + (size_t)(2 * HSZ + myunit) * HSZ + seg * 32;
#pragma unroll
    for (int u = 0; u < 8; ++u) {
      float4 a = *(const float4*)(h0 + u * 4);
      float4 b = *(const float4*)(h1 + u * 4);
      float4 c = *(const float4*)(h2 + u * 4);
      wh0[u*4+0]=a.x; wh0[u*4+1]=a.y; wh0[u*4+2]=a.z; wh0[u*4+3]=a.w;
      wh1[u*4+0]=b.x; wh1[u*4+1]=b.y; wh1[u*4+2]=b.z; wh1[u*4+3]=b.w;
      wh2[u*4+0]=c.x; wh2[u*4+1]=c.y; wh2[u*4+2]=c.z; wh2[u*4+3]=c.w;
    }
    const float* i0 = w_ih + (size_t)(0 * HSZ + myunit) * ISZ + seg * 16;
    const float* i1 = w_ih + (size_t)(1 * HSZ + myunit) * ISZ + seg * 16;
    const float* i2 = w_ih + (size_t)(2 * HSZ + myunit) * ISZ + seg * 16;
#pragma unroll
    for (int u = 0; u < 4; ++u) {
      float4 a = *(const float4*)(i0 + u * 4);
      float4 b = *(const float4*)(i1 + u * 4);
      float4 c = *(const float4*)(i2 + u * 4);
      wi0[u*4+0]=a.x; wi0[u*4+1]=a.y; wi0[u*4+2]=a.z; wi0[u*4+3]=a.w;
      wi1[u*4+0]=b.x; wi1[u*4+1]=b.y; wi1[u*4+2]=b.z; wi1[u*4+3]=b.w;
      wi2[u*4+0]=c.x; wi2[u*4+1]=c.y; wi2[u*4+2]=c.z; wi2[u*4+3]=c.w;
    }
  }
  const float br  = bias[myunit];
  const float bz  = bias[HSZ + myunit];
  const float bnn = bias[2 * HSZ + myunit];
  const float bn2 = bias_n[myunit];

  long long budget = 20000000;  // spin fuse (fail visibly, never wedge)

  if (!fast) {
    // ---- SLOW fallback: R2/R11-proven tagged agent-scope protocol ----
    float hprev = 0.f;
    for (int s = 0; s < T_TOTAL; ++s) {
      const int cur = s & 1, nxt = cur ^ 1;
      if (tid < 64) {
        float4 v = *(const float4*)(xs + (size_t)s * ISZ + tid * 4);
        *(float4*)&x_lds[cur][0][XSW(tid * 4)] = v;
      }
      __syncthreads();
      float a0 = 0.f, a1 = 0.f, a2 = 0.f, a3 = 0.f;
      IGDOTS(cur, 0);
      u64 q0;
      do {
        q0 = __hip_atomic_load(&hslow[(size_t)cur * 1024 + 2 * tid],
                               __ATOMIC_ACQUIRE, __HIP_MEMORY_SCOPE_AGENT);
      } while ((unsigned)(q0 >> 32) != (unsigned)s && --budget > 0);
      h_lds[HSW(tid)] = __uint_as_float((unsigned)q0);
      __syncthreads();
      MATVEC_BFLY();
      if (seg == 0) {
        float r  = 1.f / (1.f + __expf(-(br + a0)));
        float z  = 1.f / (1.f + __expf(-(bz + a1)));
        float tv = bnn + a2 + r * (a3 + bn2);
        float nn = 1.f - 2.f / (__expf(2.f * tv) + 1.f);
        float hold = h_lds[HSW(myunit)];
        float hnew = nn + z * (hold - nn);
        __hip_atomic_store(&hslow[(size_t)nxt * 1024 + 2 * myunit],
                           ((u64)(unsigned)(s + 1) << 32) | (u64)__float_as_uint(hnew),
                           __ATOMIC_RELEASE, __HIP_MEMORY_SCOPE_AGENT);
        out[(size_t)HSZ + (size_t)s * HSZ + myunit] = hnew;
        hprev = hnew;
      }
      __syncthreads();
    }
    if (seg == 0) out[myunit] = hprev;
    return;
  }

  // ---- FAST path ----
  // Prologue: wave 7 preloads x batch 0 (rows 0..7) into x_lds[0].
  float4 xr[XB];
  if (tid >= 448) {
    int t = tid - 448;
#pragma unroll
    for (int k = 0; k < XB; ++k) {
      float4 v = *(const float4*)(xs + (size_t)k * ISZ + t * 4);
      *(float4*)&x_lds[0][k][XSW(t * 4)] = v;
    }
  }
  __syncthreads();

  for (int s = 0; s < T_TOTAL; ++s) {
    const int cur = s & 1, nxt = cur ^ 1;
    const int xb = (s >> 3) & 1, xk = s & 7;

    // A) input-side gate dots (LDS only); then the spinner checks the counter.
    float a0 = 0.f, a1 = 0.f, a2 = 0.f, a3 = 0.f;
    IGDOTS(xb, xk);
    if (tid == SPIN) spin_cnt(hcnt, (u64)256 * (u64)s, budget);
    __syncthreads();  // B1: counter >= 256s -> all h_s slots final at TCC

    // C) batched side-traffic + one-shot h fetch.
    if (xk == 0) {
      if (s > 0 && tid >= 256 && tid < 384) {   // flush out rows s-8..s-1
        int t = tid - 256, u_ = t >> 2, p2 = t & 3;
        size_t base = (size_t)HSZ + (size_t)(s - 8) * HSZ + role * SLICE + u_;
        out[base + (size_t)(2 * p2)     * HSZ] = hq[u_ * 9 + 2 * p2];
        out[base + (size_t)(2 * p2 + 1) * HSZ] = hq[u_ * 9 + 2 * p2 + 1];
      }
      if (tid >= 448) {                          // issue next x batch loads
        int t = tid - 448, b1 = (s >> 3) + 1;
#pragma unroll
        for (int k = 0; k < XB; ++k) {
          int row = b1 * XB + k; if (row > T_TOTAL - 1) row = T_TOTAL - 1;
          xr[k] = *(const float4*)(xs + (size_t)row * ISZ + t * 4);
        }
      }
    }
    if (xk == 7 && tid >= 448) {                 // commit x batch to LDS
      int t = tid - 448, nb = ((s >> 3) + 1) & 1;
#pragma unroll
      for (int k = 0; k < XB; ++k)
        *(float4*)&x_lds[nb][k][XSW(t * 4)] = xr[k];
    }
    if (tid < 256) {                             // one-shot fetch: 2 f32 / RMW
      u64 q = rmw_read(hfast + ((size_t)cur * 256 + tid) * 4);
      float2 hv2;
      hv2.x = __uint_as_float((unsigned)q);
      hv2.y = __uint_as_float((unsigned)(q >> 32));
      *(float2*)&h_lds[HSW(2 * tid)] = hv2;
    }
    __syncthreads();  // B2: h_lds ready

    // E) hidden matvec + butterfly + epilogue/publish.
    MATVEC_BFLY();
    if (seg == 0) {
      float r  = 1.f / (1.f + __expf(-(br + a0)));
      float z  = 1.f / (1.f + __expf(-(bz + a1)));
      float tv = bnn + a2 + r * (a3 + bn2);
      float nn = 1.f - 2.f / (__expf(2.f * tv) + 1.f);  // tanh, exact limits
      float hold = h_lds[HSW(myunit)];
      float hnew = nn + z * (hold - nn);
      hq[rg * 9 + xk] = hnew;
      float partner = __shfl_xor(hnew, 16, 64);  // pair units (2k, 2k+1)
      if ((rg & 1) == 0) {
        u64 pw = ((u64)__float_as_uint(partner) << 32) | (u64)__float_as_uint(hnew);
        u64* pp = hfast + ((size_t)nxt * 256 + (role << 4) + (rg >> 1)) * 4;
        asm volatile("global_atomic_swap_x2 %0, %1, off\n\t"
                     "s_waitcnt vmcnt(0)" :: "v"(pp), "v"(pw) : "memory");
        cnt_bump(hcnt);  // +1 per publisher; step-s target = 256*s
      }
    }
    // no B3: h_lds/x_lds/hq reuse is fenced by B1/B2 of the next step.
  }

  // Tail: flush last batch (rows T-8..T-1) + final state from hq.
  if (tid < 256) {
    int u_ = tid >> 3, k = tid & 7;
    out[(size_t)HSZ + (size_t)(T_TOTAL - 8 + k) * HSZ + role * SLICE + u_] =
        hq[u_ * 9 + k];
  }
  if (tid < 32) out[role * SLICE + tid] = hq[tid * 9 + 7];
}

// ---------------------------------------------------------------------------
extern "C" void kernel_launch(void* const* d_in, const int* in_sizes, int n_in,
                              void* d_out, int out_size, void* d_ws, size_t ws_size,
                              hipStream_t stream) {
  const float* xs     = (const float*)d_in[0];
  const float* w_ih   = (const float*)d_in[1];
  const float* w_hh   = (const float*)d_in[2];
  const float* bias   = (const float*)d_in[3];
  const float* bias_n = (const float*)d_in[4];
  float* out = (float*)d_out;

  u64* hfast = (u64*)d_ws;                      // [2][256] slots x 32B = 16 KB
  u64* hcnt  = (u64*)((char*)d_ws + 16384);     // publish counter (own line)
  Ctl* ctl   = (Ctl*)((char*)d_ws + 16512);     // election control
  u64* hslow = (u64*)((char*)d_ws + 17408);     // slow-mode tagged slots 16 KB

  hipMemsetAsync(d_ws, 0, 36864, stream);       // slots/counter/ctl = 0 (h_0=0)
  gru_fused<<<256, NTHR, 0, stream>>>(xs, w_ih, w_hh, bias, bias_n,
                                      hfast, hcnt, hslow, ctl, out);
}

// Round 13
// 164225.415 us; speedup vs baseline: 2.0090x; 2.0090x over previous
//
#include <hip/hip_runtime.h>
#include <stdint.h>

typedef unsigned long long u64;
typedef unsigned int u32;
typedef float f32x32 __attribute__((ext_vector_type(32)));
typedef float f32x16 __attribute__((ext_vector_type(16)));

#define T_TOTAL 65536
#define ISZ 256
#define HSZ 512
#define NWORK 16
#define SLICE 32    // HSZ / NWORK
#define NTHR 512    // 8 waves -> 256-reg budget (R10 lesson)
#define NPOLL 128   // polling threads per block (waves 0-1)
#define STG0 384    // stager threads: tid 384..447 (wave 6)

// LDS skew (word index): +4 words per row -> max 2-way bank aliasing (free).
__device__ __forceinline__ int HSW(int i) { return i + ((i >> 5) << 2); }
__device__ __forceinline__ int XSW(int i) { return i + ((i >> 4) << 2); }

struct Ctl { int grank; int chosen; int fastctr; int done; int slowctr; int pad[11]; };

__device__ __forceinline__ void publish_swap(u64* p, u64 v) {
  asm volatile("global_atomic_swap_x2 %0, %1, off" :: "v"(p), "v"(v) : "memory");
}

// ---------------------------------------------------------------------------
// Persistent fused GRU scan, 16 blocks x 512 threads.
// R13 protocol: 2 f32 packed per 8B slot; freshness tag = 2 mantissa LSBs of
// EACH f32 forced to (step&3) (error <=3ulp, negligible). 2 parity banks of
// 256 slots. Poll-as-fetch (R12 lesson: no extra hops): 128 pollers/block,
// 2 TCC RMWs in flight each, one vmcnt(0) -> 4096-RMW bursts (half of R11).
// Tag safety: s vs s-2 differ in s&3; s-4 impossible because this poller's
// own iter-(s-2) detect confirmed generation s-2 reached the slot.
// Raw s_barrier + manual lgkmcnt(0) (NO vmcnt drain): stagers' HBM x-loads
// and publish swaps are never drained at the barrier (R8's hidden chain cost).
// out[] stores: epilogue -> hq[2][32] LDS -> stager global store 2 steps
// later (all ordering via the single per-step barrier).
// FAST mode (16 workers verified on ONE XCD, TCC RMWs = R6-proven);
// SLOW fallback: full-tag agent-scope protocol (R2-proven).
// Spin fuse bounds worst-case runtime (fail visibly, never wedge).
// ---------------------------------------------------------------------------
__global__ __launch_bounds__(NTHR, 1) void gru_fused(
    const float* __restrict__ xs, const float* __restrict__ w_ih,
    const float* __restrict__ w_hh, const float* __restrict__ bias,
    const float* __restrict__ bias_n, u64* __restrict__ hfast,
    u64* __restrict__ hslow, Ctl* __restrict__ ctl,
    float* __restrict__ out) {
  const int tid = threadIdx.x;
  const int seg = tid & 15;   // K-segment: h[32*seg..+32), x[16*seg..+16)
  const int rg  = tid >> 4;   // unit within slice (0..31)

  __shared__ int s_role, s_fast;
  __shared__ __align__(16) float x_lds[2][320];
  __shared__ __align__(16) float h_lds[2][576];
  __shared__ __align__(16) float hq[2][32];   // epilogue -> stager handoff

  // ---- election: verify 16 blocks on one XCD, else agent-scope fallback
  if (tid == 0) {
    unsigned xcc = 0;
    asm volatile("s_getreg_b32 %0, hwreg(HW_REG_XCC_ID)" : "=s"(xcc));
    long long eb = 100000000;
    int rank = __hip_atomic_fetch_add(&ctl->grank, 1, __ATOMIC_RELAXED,
                                      __HIP_MEMORY_SCOPE_AGENT);
    if (rank == 0)
      __hip_atomic_store(&ctl->chosen, (int)xcc + 1, __ATOMIC_RELEASE,
                         __HIP_MEMORY_SCOPE_AGENT);
    int chosen;
    do { chosen = __hip_atomic_load(&ctl->chosen, __ATOMIC_ACQUIRE,
                                    __HIP_MEMORY_SCOPE_AGENT); }
    while (chosen == 0 && --eb > 0);
    int fr = -1;
    if ((int)xcc == chosen - 1)
      fr = __hip_atomic_fetch_add(&ctl->fastctr, 1, __ATOMIC_RELAXED,
                                  __HIP_MEMORY_SCOPE_AGENT);
    __hip_atomic_fetch_add(&ctl->done, 1, __ATOMIC_ACQ_REL,
                           __HIP_MEMORY_SCOPE_AGENT);
    int dn;
    do { dn = __hip_atomic_load(&ctl->done, __ATOMIC_ACQUIRE,
                                __HIP_MEMORY_SCOPE_AGENT); }
    while (dn < (int)gridDim.x && --eb > 0);
    int fc = __hip_atomic_load(&ctl->fastctr, __ATOMIC_ACQUIRE,
                               __HIP_MEMORY_SCOPE_AGENT);
    int fast = (fc >= NWORK && dn >= (int)gridDim.x) ? 1 : 0;
    int role = -1;
    if (fast) {
      if (fr >= 0 && fr < NWORK) role = fr;
    } else {
      int sr = __hip_atomic_fetch_add(&ctl->slowctr, 1, __ATOMIC_RELAXED,
                                      __HIP_MEMORY_SCOPE_AGENT);
      if (sr < NWORK) role = sr;
    }
    s_role = role; s_fast = fast;
  }
  __syncthreads();
  const int role = s_role;   // uniform per block
  const int fast = s_fast;
  if (role < 0) return;      // whole block exits together

  // ---- weights into registers (ext_vector, static indexing; R8-proven) ----
  const int myunit = role * SLICE + rg;
  f32x32 wh0, wh1, wh2;
  f32x16 wi0, wi1, wi2;
  {
    const float* h0 = w_hh + (size_t)(0 * HSZ + myunit) * HSZ + seg * 32;
    const float* h1 = w_hh + (size_t)(1 * HSZ + myunit) * HSZ + seg * 32;
    const float* h2 = w_hh + (size_t)(2 * HSZ + myunit) * HSZ + seg * 32;
#pragma unroll
    for (int u = 0; u < 8; ++u) {
      float4 a = *(const float4*)(h0 + u * 4);
      float4 b = *(const float4*)(h1 + u * 4);
      float4 c = *(const float4*)(h2 + u * 4);
      wh0[u*4+0]=a.x; wh0[u*4+1]=a.y; wh0[u*4+2]=a.z; wh0[u*4+3]=a.w;
      wh1[u*4+0]=b.x; wh1[u*4+1]=b.y; wh1[u*4+2]=b.z; wh1[u*4+3]=b.w;
      wh2[u*4+0]=c.x; wh2[u*4+1]=c.y; wh2[u*4+2]=c.z; wh2[u*4+3]=c.w;
    }
    const float* i0 = w_ih + (size_t)(0 * HSZ + myunit) * ISZ + seg * 16;
    const float* i1 = w_ih + (size_t)(1 * HSZ + myunit) * ISZ + seg * 16;
    const float* i2 = w_ih + (size_t)(2 * HSZ + myunit) * ISZ + seg * 16;
#pragma unroll
    for (int u = 0; u < 4; ++u) {
      float4 a = *(const float4*)(i0 + u * 4);
      float4 b = *(const float4*)(i1 + u * 4);
      float4 c = *(const float4*)(i2 + u * 4);
      wi0[u*4+0]=a.x; wi0[u*4+1]=a.y; wi0[u*4+2]=a.z; wi0[u*4+3]=a.w;
      wi1[u*4+0]=b.x; wi1[u*4+1]=b.y; wi1[u*4+2]=b.z; wi1[u*4+3]=b.w;
      wi2[u*4+0]=c.x; wi2[u*4+1]=c.y; wi2[u*4+2]=c.z; wi2[u*4+3]=c.w;
    }
  }
  const float br  = bias[myunit];
  const float bz  = bias[HSZ + myunit];
  const float bnn = bias[2 * HSZ + myunit];
  const float bn2 = bias_n[myunit];

  long long budget = 20000000;  // spin fuse (fail visibly, never wedge)

  if (!fast) {
    // ---- SLOW fallback: R2-proven full-tag agent-scope protocol ----
    float hprev = 0.f;
    for (int s = 0; s < T_TOTAL; ++s) {
      if (tid < 64) {
        float4 v = *(const float4*)(xs + (size_t)s * ISZ + tid * 4);
        *(float4*)&x_lds[0][XSW(tid * 4)] = v;
      }
      __syncthreads();
      float a0 = 0.f, a1 = 0.f, a2 = 0.f, a3 = 0.f;
#pragma unroll
      for (int u = 0; u < 4; ++u) {
        float4 xv = *(const float4*)&x_lds[0][XSW(seg * 16 + u * 4)];
        a0 += wi0[u*4+0]*xv.x + wi0[u*4+1]*xv.y + wi0[u*4+2]*xv.z + wi0[u*4+3]*xv.w;
        a1 += wi1[u*4+0]*xv.x + wi1[u*4+1]*xv.y + wi1[u*4+2]*xv.z + wi1[u*4+3]*xv.w;
        a2 += wi2[u*4+0]*xv.x + wi2[u*4+1]*xv.y + wi2[u*4+2]*xv.z + wi2[u*4+3]*xv.w;
      }
      const int cur = s & 1, nxt = cur ^ 1;
      u64 q0;
      do {
        q0 = __hip_atomic_load(&hslow[(size_t)cur * 1024 + 2 * tid],
                               __ATOMIC_ACQUIRE, __HIP_MEMORY_SCOPE_AGENT);
      } while ((unsigned)(q0 >> 32) != (unsigned)s && --budget > 0);
      h_lds[cur][HSW(tid)] = __uint_as_float((u32)q0);
      __syncthreads();
#pragma unroll
      for (int u = 0; u < 8; ++u) {
        float4 hv = *(const float4*)&h_lds[cur][HSW(seg * 32 + u * 4)];
        a0 += wh0[u*4+0]*hv.x + wh0[u*4+1]*hv.y + wh0[u*4+2]*hv.z + wh0[u*4+3]*hv.w;
        a1 += wh1[u*4+0]*hv.x + wh1[u*4+1]*hv.y + wh1[u*4+2]*hv.z + wh1[u*4+3]*hv.w;
        a3 += wh2[u*4+0]*hv.x + wh2[u*4+1]*hv.y + wh2[u*4+2]*hv.z + wh2[u*4+3]*hv.w;
      }
#pragma unroll
      for (int p = 0; p < 4; ++p) {
        int m = 1 << p;
        a0 += __shfl_xor(a0, m, 64);
        a1 += __shfl_xor(a1, m, 64);
        a2 += __shfl_xor(a2, m, 64);
        a3 += __shfl_xor(a3, m, 64);
      }
      if (seg == 0) {
        float r  = 1.f / (1.f + __expf(-(br + a0)));
        float z  = 1.f / (1.f + __expf(-(bz + a1)));
        float tv = bnn + a2 + r * (a3 + bn2);
        float nn = 1.f - 2.f / (__expf(2.f * tv) + 1.f);
        float hold = h_lds[cur][HSW(myunit)];
        float hnew = nn + z * (hold - nn);
        __hip_atomic_store(&hslow[(size_t)nxt * 1024 + 2 * myunit],
                           ((u64)(u32)(s + 1) << 32) | (u64)__float_as_uint(hnew),
                           __ATOMIC_RELEASE, __HIP_MEMORY_SCOPE_AGENT);
        out[(size_t)HSZ + (size_t)s * HSZ + myunit] = hnew;
        hprev = hnew;
      }
      __syncthreads();
    }
    if (seg == 0) out[myunit] = hprev;
    return;
  }

  // ---- FAST path prologue: stagers load x[0]->LDS bank0, x[1]->regs ----
  float4 xreg{};
  if (tid >= STG0 && tid < STG0 + 64) {
    int st = tid - STG0;
    float4 t0 = *(const float4*)(xs + st * 4);
    *(float4*)&x_lds[0][XSW(st * 4)] = t0;
    xreg = *(const float4*)(xs + (size_t)ISZ + st * 4);
  }
  __syncthreads();

  for (int s = 0; s < T_TOTAL; ++s) {
    const int cur = s & 1, nxt = cur ^ 1;
    const u32 tg = (u32)s & 3;

    // 1) input-side gate dots (LDS only). a3 = hidden-side n, kept separate.
    float a0 = 0.f, a1 = 0.f, a2 = 0.f, a3 = 0.f;
#pragma unroll
    for (int u = 0; u < 4; ++u) {
      float4 xv = *(const float4*)&x_lds[cur][XSW(seg * 16 + u * 4)];
      a0 += wi0[u*4+0]*xv.x + wi0[u*4+1]*xv.y + wi0[u*4+2]*xv.z + wi0[u*4+3]*xv.w;
      a1 += wi1[u*4+0]*xv.x + wi1[u*4+1]*xv.y + wi1[u*4+2]*xv.z + wi1[u*4+3]*xv.w;
      a2 += wi2[u*4+0]*xv.x + wi2[u*4+1]*xv.y + wi2[u*4+2]*xv.z + wi2[u*4+3]*xv.w;
    }

    // 2) stagers: out row s-2 from hq (fire-and-forget), x commit + prefetch.
    if (tid >= STG0 && tid < STG0 + 64) {
      int st = tid - STG0;
      if (s >= 2 && st < 8) {
        float4 ov = *(const float4*)&hq[cur][4 * st];   // written iter s-2
        *(float4*)(out + HSZ + (size_t)(s - 2) * HSZ + role * SLICE + 4 * st) = ov;
      }
      *(float4*)&x_lds[nxt][XSW(st * 4)] = xreg;        // commit x[s+1]
      int srow = (s + 2 < T_TOTAL) ? (s + 2) : (T_TOTAL - 1);
      xreg = *(const float4*)(xs + (size_t)srow * ISZ + st * 4);  // issue x[s+2]
    }

    // 3) pollers: 2 packed slots each (4 h values), 2 TCC RMWs in flight.
    if (tid < NPOLL) {
      u64* bank = hfast + (size_t)cur * 512;
      u64* p0 = bank + 4 * tid;       // slot 2*tid   (16B stride)
      u64* p1 = bank + 4 * tid + 2;   // slot 2*tid+1
      u64 q0, q1, zero = 0;
      for (;;) {
        asm volatile("global_atomic_add_x2 %0, %2, %4, off sc0\n\t"
                     "global_atomic_add_x2 %1, %3, %4, off sc0\n\t"
                     "s_waitcnt vmcnt(0)"
                     : "=&v"(q0), "=&v"(q1)
                     : "v"(p0), "v"(p1), "v"(zero)
                     : "memory");
        u32 bad = (((u32)q0 ^ tg) & 3u) | (((u32)(q0 >> 32) ^ tg) & 3u) |
                  (((u32)q1 ^ tg) & 3u) | (((u32)(q1 >> 32) ^ tg) & 3u);
        if (bad == 0) break;
        if (--budget <= 0) break;
      }
      float4 hv;
      hv.x = __uint_as_float((u32)q0);
      hv.y = __uint_as_float((u32)(q0 >> 32));
      hv.z = __uint_as_float((u32)q1);
      hv.w = __uint_as_float((u32)(q1 >> 32));
      *(float4*)&h_lds[cur][HSW(4 * tid)] = hv;
    }

    // B2: LDS visibility only — NO vmcnt drain (keeps stager HBM ops and
    // publish swaps off the barrier; that drain was R8's hidden chain cost).
    asm volatile("s_waitcnt lgkmcnt(0)\n\ts_barrier" ::: "memory");

    // 4) hidden-side dots (critical chain) + butterfly.
#pragma unroll
    for (int u = 0; u < 8; ++u) {
      float4 hv = *(const float4*)&h_lds[cur][HSW(seg * 32 + u * 4)];
      a0 += wh0[u*4+0]*hv.x + wh0[u*4+1]*hv.y + wh0[u*4+2]*hv.z + wh0[u*4+3]*hv.w;
      a1 += wh1[u*4+0]*hv.x + wh1[u*4+1]*hv.y + wh1[u*4+2]*hv.z + wh1[u*4+3]*hv.w;
      a3 += wh2[u*4+0]*hv.x + wh2[u*4+1]*hv.y + wh2[u*4+2]*hv.z + wh2[u*4+3]*hv.w;
    }
#pragma unroll
    for (int p = 0; p < 4; ++p) {
      int m = 1 << p;
      a0 += __shfl_xor(a0, m, 64);
      a1 += __shfl_xor(a1, m, 64);
      a2 += __shfl_xor(a2, m, 64);
      a3 += __shfl_xor(a3, m, 64);
    }

    // 5) epilogue: hq handoff + tagged packed publish (chain edge, earliest).
    if (seg == 0) {
      float r  = 1.f / (1.f + __expf(-(br + a0)));
      float z  = 1.f / (1.f + __expf(-(bz + a1)));
      float tv = bnn + a2 + r * (a3 + bn2);
      float nn = 1.f - 2.f / (__expf(2.f * tv) + 1.f);  // tanh, exact limits
      float hold = h_lds[cur][HSW(myunit)];
      float hnew = nn + z * (hold - nn);
      u32 tb = (u32)(s + 1) & 3u;
      u32 bbits = (__float_as_uint(hnew) & ~3u) | tb;   // steal 2 mantissa LSBs
      float tagged = __uint_as_float(bbits);
      float partner = __shfl_xor(tagged, 16, 64);       // pair (2k, 2k+1)
      if ((rg & 1) == 0) {
        u64 pw = ((u64)__float_as_uint(partner) << 32) | (u64)bbits;
        u64* pp = hfast + (size_t)nxt * 512 + 2 * (role * 16 + (rg >> 1));
        publish_swap(pp, pw);
      }
      hq[cur][rg] = hnew;   // clean value; stager stores it at iter s+2
    }
    // No end barrier: all cross-phase reuse is ordered by B2 (parity proofs
    // in header comment; hq read@s+2 is pre-B2(s+2), write@s+2 post-B2(s+2)).
  }

  // Tail: rows T-2, T-1 and final state from hq (barrier for visibility).
  asm volatile("s_waitcnt lgkmcnt(0)\n\ts_barrier" ::: "memory");
  if (tid >= STG0 && tid < STG0 + 8) {
    int st4 = (tid - STG0) * 4;
    float4 a = *(const float4*)&hq[(T_TOTAL - 2) & 1][st4];
    float4 b = *(const float4*)&hq[(T_TOTAL - 1) & 1][st4];
    *(float4*)(out + HSZ + (size_t)(T_TOTAL - 2) * HSZ + role * SLICE + st4) = a;
    *(float4*)(out + HSZ + (size_t)(T_TOTAL - 1) * HSZ + role * SLICE + st4) = b;
    *(float4*)(out + role * SLICE + st4) = b;   // final state = h_T
  }
}

// ---------------------------------------------------------------------------
extern "C" void kernel_launch(void* const* d_in, const int* in_sizes, int n_in,
                              void* d_out, int out_size, void* d_ws, size_t ws_size,
                              hipStream_t stream) {
  const float* xs     = (const float*)d_in[0];
  const float* w_ih   = (const float*)d_in[1];
  const float* w_hh   = (const float*)d_in[2];
  const float* bias   = (const float*)d_in[3];
  const float* bias_n = (const float*)d_in[4];
  float* out = (float*)d_out;

  u64* hfast = (u64*)d_ws;                      // [2][256] packed slots, 16B stride = 8 KB
  Ctl* ctl   = (Ctl*)((char*)d_ws + 8192);      // election control
  u64* hslow = (u64*)((char*)d_ws + 8448);      // slow-mode tagged slots 16 KB

  hipMemsetAsync(d_ws, 0, 24832, stream);       // h_0 = 0 (tag 0 = step 0); ctl = 0
  gru_fused<<<256, NTHR, 0, stream>>>(xs, w_ih, w_hh, bias, bias_n,
                                      hfast, hslow, ctl, out);
}

// Round 14
// 98095.020 us; speedup vs baseline: 3.3634x; 1.6741x over previous
//
#include <hip/hip_runtime.h>
#include <stdint.h>

typedef unsigned long long u64;
typedef float f32x32 __attribute__((ext_vector_type(32)));
typedef float f32x16 __attribute__((ext_vector_type(16)));

#define T_TOTAL 65536
#define ISZ 256
#define HSZ 512
#define NWORK 16
#define SLICE 32   // HSZ / NWORK
#define NTHR 512   // 8 waves: even 2/SIMD split -> 256-reg budget (R10 lesson)

// LDS skew (word index): +4 words per row -> max 2-way bank aliasing (free).
__device__ __forceinline__ int HSW(int i) { return i + ((i >> 5) << 2); }  // rows of 32
__device__ __forceinline__ int XSW(int i) { return i + ((i >> 4) << 2); }  // rows of 16

struct Ctl { int grank; int chosen; int fastctr; int done; int slowctr; int pad[11]; };

// R14 publish: PLAIN 8B store. CDNA vector L1 is write-through, so the value
// is in the XCD's L2 immediately — no scope flag, no MALL write-through (the
// WRITE_SIZE evidence says sc0 atomics were all going device-scope/MALL).
__device__ __forceinline__ void publish_store(u64* p, u64 v) {
  asm volatile("global_store_dwordx2 %0, %1, off" :: "v"(p), "v"(v) : "memory");
}

// R14 poll: L2 read path. buffer_inv (drop stale vL1 lines) must COMPLETE
// before the load issues -> s_waitcnt between them (R7 lacked this). Loads of
// a shared line replicate in parallel at L2 (no TCC serialization). 8B
// aligned loads are single-copy atomic (R2's passing protocol proves it).
// STICKY FALLBACK: after 64 stale rounds this thread permanently switches to
// the R8-proven sc0 RMW poll — worst case the kernel runs at R8 speed.
__device__ __forceinline__ u64 poll1_hybrid(u64* p, unsigned sv,
                                            long long& budget, int& sticky) {
  u64 q;
  if (!sticky) {
    for (int i = 0; i < 64; ++i) {
      asm volatile("buffer_inv\n\t"
                   "s_waitcnt vmcnt(0)\n\t"
                   "global_load_dwordx2 %0, %1, off sc0 nt\n\t"
                   "s_waitcnt vmcnt(0)"
                   : "=&v"(q) : "v"(p) : "memory");
      if ((unsigned)(q >> 32) == sv) return q;
    }
    sticky = 1;  // loads are stale-stuck on this slot: use RMWs from now on
  }
  u64 zero = 0;
  for (;;) {
    asm volatile("global_atomic_add_x2 %0, %1, %2, off sc0\n\t"
                 "s_waitcnt vmcnt(0)"
                 : "=&v"(q) : "v"(p), "v"(zero) : "memory");
    if ((unsigned)(q >> 32) == sv) break;
    if (--budget <= 0) break;
  }
  return q;
}

// ---------------------------------------------------------------------------
// Persistent fused GRU scan, 16 blocks x 512 threads (R8 shell, proven).
// R8 -> R14 change: sync primitives only. Publish = plain store (L2 via
// write-through L1); poll = buffer_inv + L2 load with sticky RMW fallback.
// Sync: tagged 64-bit slots {tag=version, f32 value}, 16B-padded, parity-2
// ring. FAST mode (16 workers verified on ONE XCD; L2 is the intra-XCD
// coherence point for both stores and TCC RMWs). SLOW fallback: agent-scope
// acquire/release (R2-proven).
//
// Memory-safety with ONE barrier (B2) per step (R8's proof carries over):
//  - h_lds double-buffered by parity; reuse at s+2 gated by poll(s+2): tag
//    s+2 implies every block passed B2(s+1), i.e. finished iter s reads.
//  - x_lds double-buffered: writes@s+1 after B2(s); reads@s before B2(s).
// Spin fuse bounds worst-case runtime (fail visibly, never wedge).
// ---------------------------------------------------------------------------
__global__ __launch_bounds__(NTHR, 1) void gru_fused(
    const float* __restrict__ xs, const float* __restrict__ w_ih,
    const float* __restrict__ w_hh, const float* __restrict__ bias,
    const float* __restrict__ bias_n, u64* __restrict__ hslot,
    Ctl* __restrict__ ctl, float* __restrict__ out) {
  const int tid = threadIdx.x;
  const int seg = tid & 15;   // K-segment: h[32*seg..+32), x[16*seg..+16)
  const int rg  = tid >> 4;   // unit within slice (0..31)

  __shared__ int s_role, s_fast;
  __shared__ __align__(16) float x_lds[2][320];
  __shared__ __align__(16) float h_lds[2][576];

  // ---- election: verify 16 blocks on one XCD, else agent-scope fallback
  if (tid == 0) {
    unsigned xcc = 0;
    asm volatile("s_getreg_b32 %0, hwreg(HW_REG_XCC_ID)" : "=s"(xcc));
    long long eb = 100000000;
    int rank = __hip_atomic_fetch_add(&ctl->grank, 1, __ATOMIC_RELAXED,
                                      __HIP_MEMORY_SCOPE_AGENT);
    if (rank == 0)
      __hip_atomic_store(&ctl->chosen, (int)xcc + 1, __ATOMIC_RELEASE,
                         __HIP_MEMORY_SCOPE_AGENT);
    int chosen;
    do { chosen = __hip_atomic_load(&ctl->chosen, __ATOMIC_ACQUIRE,
                                    __HIP_MEMORY_SCOPE_AGENT); }
    while (chosen == 0 && --eb > 0);
    int fr = -1;
    if ((int)xcc == chosen - 1)
      fr = __hip_atomic_fetch_add(&ctl->fastctr, 1, __ATOMIC_RELAXED,
                                  __HIP_MEMORY_SCOPE_AGENT);
    __hip_atomic_fetch_add(&ctl->done, 1, __ATOMIC_ACQ_REL,
                           __HIP_MEMORY_SCOPE_AGENT);
    int dn;
    do { dn = __hip_atomic_load(&ctl->done, __ATOMIC_ACQUIRE,
                                __HIP_MEMORY_SCOPE_AGENT); }
    while (dn < (int)gridDim.x && --eb > 0);
    int fc = __hip_atomic_load(&ctl->fastctr, __ATOMIC_ACQUIRE,
                               __HIP_MEMORY_SCOPE_AGENT);
    int fast = (fc >= NWORK && dn >= (int)gridDim.x) ? 1 : 0;
    int role = -1;
    if (fast) {
      if (fr >= 0 && fr < NWORK) role = fr;
    } else {
      int sr = __hip_atomic_fetch_add(&ctl->slowctr, 1, __ATOMIC_RELAXED,
                                      __HIP_MEMORY_SCOPE_AGENT);
      if (sr < NWORK) role = sr;
    }
    s_role = role; s_fast = fast;
  }
  __syncthreads();
  const int role = s_role;   // uniform per block
  const int fast = s_fast;
  if (role < 0) return;      // whole block exits together

  // ---- weights into registers (ext_vector, static indexing; R8-proven) ----
  const int myunit = role * SLICE + rg;
  f32x32 wh0, wh1, wh2;
  f32x16 wi0, wi1, wi2;
  {
    const float* h0 = w_hh + (size_t)(0 * HSZ + myunit) * HSZ + seg * 32;
    const float* h1 = w_hh + (size_t)(1 * HSZ + myunit) * HSZ + seg * 32;
    const float* h2 = w_hh + (size_t)(2 * HSZ + myunit) * HSZ + seg * 32;
#pragma unroll
    for (int u = 0; u < 8; ++u) {
      float4 a = *(const float4*)(h0 + u * 4);
      float4 b = *(const float4*)(h1 + u * 4);
      float4 c = *(const float4*)(h2 + u * 4);
      wh0[u*4+0]=a.x; wh0[u*4+1]=a.y; wh0[u*4+2]=a.z; wh0[u*4+3]=a.w;
      wh1[u*4+0]=b.x; wh1[u*4+1]=b.y; wh1[u*4+2]=b.z; wh1[u*4+3]=b.w;
      wh2[u*4+0]=c.x; wh2[u*4+1]=c.y; wh2[u*4+2]=c.z; wh2[u*4+3]=c.w;
    }
    const float* i0 = w_ih + (size_t)(0 * HSZ + myunit) * ISZ + seg * 16;
    const float* i1 = w_ih + (size_t)(1 * HSZ + myunit) * ISZ + seg * 16;
    const float* i2 = w_ih + (size_t)(2 * HSZ + myunit) * ISZ + seg * 16;
#pragma unroll
    for (int u = 0; u < 4; ++u) {
      float4 a = *(const float4*)(i0 + u * 4);
      float4 b = *(const float4*)(i1 + u * 4);
      float4 c = *(const float4*)(i2 + u * 4);
      wi0[u*4+0]=a.x; wi0[u*4+1]=a.y; wi0[u*4+2]=a.z; wi0[u*4+3]=a.w;
      wi1[u*4+0]=b.x; wi1[u*4+1]=b.y; wi1[u*4+2]=b.z; wi1[u*4+3]=b.w;
      wi2[u*4+0]=c.x; wi2[u*4+1]=c.y; wi2[u*4+2]=c.z; wi2[u*4+3]=c.w;
    }
  }
  const float br  = bias[myunit];
  const float bz  = bias[HSZ + myunit];
  const float bnn = bias[2 * HSZ + myunit];
  const float bn2 = bias_n[myunit];

  // prologue: x[0] -> LDS buf0; xreg holds x[1]
  float4 xreg{};
  if (tid < 64) {
    float4 t0 = *(const float4*)(xs + tid * 4);
    *(float4*)&x_lds[0][XSW(tid * 4)] = t0;
    xreg = *(const float4*)(xs + (size_t)ISZ + tid * 4);
  }
  __syncthreads();

  long long budget = 20000000;  // spin fuse (fail visibly, never wedge)
  int sticky = 0;               // per-thread: load-poll until proven stale

  for (int s = 0; s < T_TOTAL; ++s) {
    const int cur = s & 1, nxt = cur ^ 1;

    // x[s+1] prefetch (off-chain; HBM latency hides under the h-wait).
    float4 xpf;
    if (tid < 64) {
      int srow = (s + 1 < T_TOTAL) ? (s + 1) : s;
      xpf = *(const float4*)(xs + (size_t)srow * ISZ + tid * 4);
    }

    // Input-side gate dots (independent of h). a3 = hidden-side n, separate.
    float a0 = 0.f, a1 = 0.f, a2 = 0.f, a3 = 0.f;
#pragma unroll
    for (int u = 0; u < 4; ++u) {
      float4 xv = *(const float4*)&x_lds[cur][XSW(seg * 16 + u * 4)];
      a0 += wi0[u*4+0]*xv.x + wi0[u*4+1]*xv.y + wi0[u*4+2]*xv.z + wi0[u*4+3]*xv.w;
      a1 += wi1[u*4+0]*xv.x + wi1[u*4+1]*xv.y + wi1[u*4+2]*xv.z + wi1[u*4+3]*xv.w;
      a2 += wi2[u*4+0]*xv.x + wi2[u*4+1]*xv.y + wi2[u*4+2]*xv.z + wi2[u*4+3]*xv.w;
    }
    if (tid < 64) *(float4*)&x_lds[nxt][XSW(tid * 4)] = xpf;  // after B2(s-1)

    // Poll h version s (1 slot/thread, 16B padded).
    u64* sb = hslot + (size_t)cur * (HSZ * 2);
    u64 q0;
    if (fast) {
      q0 = poll1_hybrid(&sb[2 * tid], (unsigned)s, budget, sticky);
    } else {
      do {
        q0 = __hip_atomic_load(&sb[2 * tid], __ATOMIC_ACQUIRE,
                               __HIP_MEMORY_SCOPE_AGENT);
      } while ((unsigned)(q0 >> 32) != (unsigned)s && --budget > 0);
    }
    h_lds[cur][HSW(tid)] = __uint_as_float((unsigned)q0);
    __syncthreads();  // B2: h + x[nxt] staged; the only barrier per step

    // Hidden-side dots (critical chain): 3 rows x 32-wide segment.
#pragma unroll
    for (int u = 0; u < 8; ++u) {
      float4 hv = *(const float4*)&h_lds[cur][HSW(seg * 32 + u * 4)];
      a0 += wh0[u*4+0]*hv.x + wh0[u*4+1]*hv.y + wh0[u*4+2]*hv.z + wh0[u*4+3]*hv.w;
      a1 += wh1[u*4+0]*hv.x + wh1[u*4+1]*hv.y + wh1[u*4+2]*hv.z + wh1[u*4+3]*hv.w;
      a3 += wh2[u*4+0]*hv.x + wh2[u*4+1]*hv.y + wh2[u*4+2]*hv.z + wh2[u*4+3]*hv.w;
    }
#pragma unroll
    for (int p = 0; p < 4; ++p) {
      int m = 1 << p;
      a0 += __shfl_xor(a0, m, 64);
      a1 += __shfl_xor(a1, m, 64);
      a2 += __shfl_xor(a2, m, 64);
      a3 += __shfl_xor(a3, m, 64);
    }

    // Epilogue + publish (chain edge first), then out store.
    if (seg == 0) {
      float r  = 1.f / (1.f + __expf(-(br + a0)));
      float z  = 1.f / (1.f + __expf(-(bz + a1)));
      float tv = bnn + a2 + r * (a3 + bn2);
      float nn = 1.f - 2.f / (__expf(2.f * tv) + 1.f);  // tanh, exact limits
      float hold = h_lds[cur][HSW(myunit)];
      float hnew = nn + z * (hold - nn);
      u64 pw = ((u64)(unsigned)(s + 1) << 32) | (u64)__float_as_uint(hnew);
      u64* pp = &hslot[(size_t)nxt * (HSZ * 2) + 2 * myunit];
      if (fast)
        publish_store(pp, pw);
      else
        __hip_atomic_store(pp, pw, __ATOMIC_RELEASE, __HIP_MEMORY_SCOPE_AGENT);
      out[(size_t)HSZ + (size_t)s * HSZ + myunit] = hnew;
      if (s == T_TOTAL - 1) out[myunit] = hnew;
    }
  }
}

// ---------------------------------------------------------------------------
extern "C" void kernel_launch(void* const* d_in, const int* in_sizes, int n_in,
                              void* d_out, int out_size, void* d_ws, size_t ws_size,
                              hipStream_t stream) {
  const float* xs     = (const float*)d_in[0];
  const float* w_ih   = (const float*)d_in[1];
  const float* w_hh   = (const float*)d_in[2];
  const float* bias   = (const float*)d_in[3];
  const float* bias_n = (const float*)d_in[4];
  float* out   = (float*)d_out;
  u64*   hslot = (u64*)d_ws;                    // [2][512] padded slots = 16 KB
  Ctl*   ctl   = (Ctl*)((char*)d_ws + 16384);   // election control

  hipMemsetAsync(d_ws, 0, 16384 + 256, stream); // tags=0 => h_0 = 0; ctl = 0
  gru_fused<<<256, NTHR, 0, stream>>>(xs, w_ih, w_hh, bias, bias_n, hslot, ctl, out);
}